// Round 9
// baseline (340.934 us; speedup 1.0000x reference)
//
#include <hip/hip_runtime.h>
#include <hip/hip_fp16.h>

constexpr int N_CLUSTERS   = 131072;
constexpr int N_CENTROIDS  = 256;
constexpr int D_FEAT       = 64;

constexpr int THREADS        = 1024;  // 16 waves
constexpr int ROWS_PER_BLOCK = 256;   // 16 clusters per wave

// Finite-in-bf16 sentinel for masked (cross-batch) outputs.
#define MASK_VAL (-1.0e30f)
// Mask detector: true d^2 <= 3*127^2 = 48387; cross-batch adds W*(db)^2 >= 2^17.
#define TH_MASK  (65536.0f)

typedef __attribute__((ext_vector_type(8))) short bf16x8;   // 8 bf16 (4 VGPRs)
typedef __attribute__((ext_vector_type(4))) float f32x4;    // MFMA C/D
typedef __attribute__((ext_vector_type(2))) __fp16 h2;      // cvt_pkrtz result

// fp32 pair -> packed bf16 via ONE v_perm_b32 (truncation; exact for the
// integer-valued inputs used here).
static __device__ inline unsigned pk2t(float a, float b) {
    return __builtin_amdgcn_perm(__float_as_uint(b), __float_as_uint(a), 0x07060302u);
}
// fp32 x4 -> packed 4 x f16 in one u32 (2x v_cvt_pkrtz_f16_f32 + 1 v_perm)
static __device__ inline unsigned pk4h(float a, float b, float c, float d) {
    h2 p01 = __builtin_amdgcn_cvt_pkrtz(a, b);
    h2 p23 = __builtin_amdgcn_cvt_pkrtz(c, d);
    unsigned lo, hi;
    __builtin_memcpy(&lo, &p01, 4);
    __builtin_memcpy(&hi, &p23, 4);
    return __builtin_amdgcn_perm(hi, lo, 0x05040100u);
}
static __device__ inline float h2f_lo(unsigned u) {
    return __half2float(__ushort_as_half((unsigned short)(u & 0xFFFFu)));
}
static __device__ inline float h2f_hi(unsigned u) {
    return __half2float(__ushort_as_half((unsigned short)(u >> 16)));
}

// ROUND 19 — STORE-STREAM ISOLATION DIAGNOSTIC (mirrors removed next round).
// Round-8 (128-B stores) gained only ~4.5 us of the predicted ~18. Ambiguity:
// (a) stores now fast, a ~20 us non-store floor was revealed; or (b) the
// 128-B/1-KB-stride pattern is still rate-limited. This build stores each
// output uint4 TWICE MORE into the 512-MiB workspace (distinct addresses ->
// real HBM traffic, no L2 dedup, no DSE; data already in regs so marginal
// cost = pure store BW of the exact same pattern).
//   Delta(headline - 163.5) = 268 MB / R_store:
//     ~+40 us  => R ~ 6.8 TB/s => pattern fine  -> attack epilogue pipeline
//     ~+78 us  => R ~ 3.4 TB/s => still capped  -> contiguous-1KB restructure
// Dispatch lands in top-5 => full counter row (VALUBusy / Occupancy / LDS
// conflicts) for the CURRENT structure.
//
// LDS: Bl 32768 + Atab 4128 + St 32768 = 69664 B -> 2 blocks/CU x 16
// waves = 32 waves/CU via __launch_bounds__(1024, 8).
__global__ __launch_bounds__(THREADS, 8)
void instance_head_kernel(const int*   __restrict__ clu_coords,   // [N,4] {b,x,y,z}
                          const float* __restrict__ clu_feats,    // [N,64]
                          const int*   __restrict__ cen_coords,   // [M,4]
                          const float* __restrict__ cen_feats,    // [M,64]
                          float*       __restrict__ out,          // [N,M]
                          float*       __restrict__ wsm,          // diag mirror
                          int                       mirror)
{
    __shared__ unsigned Bl[16 * 2 * 64 * 4];   // 32 KB, centroid-feat fragments
    __shared__ uint4    Atab[N_CENTROIDS + 2]; // 4128 B, coord A-frags + consts
    __shared__ uint4    St[16 * 128];          // 32 KB, per-wave store-stage slices

    const int t    = threadIdx.x;
    const int lane = t & 63;
    const int wave = __builtin_amdgcn_readfirstlane(t >> 6);
    const int m    = lane & 15;
    const int quad = lane >> 4;
    const int r0w  = blockIdx.x * ROWS_PER_BLOCK + wave * 16;

    // ---- B operand: this lane's cluster feats (coalesced fp32 loads) ----
    // frag f, lane: B[col = m][k = f*32 + quad*8 + j]
    const float* bptr = clu_feats + (size_t)(r0w + m) * D_FEAT + quad * 8;
    const float4 bL0 = *(const float4*)(bptr);
    const float4 bH0 = *(const float4*)(bptr + 4);
    const float4 bL1 = *(const float4*)(bptr + 32);
    const float4 bH1 = *(const float4*)(bptr + 36);

    // ---- stage centroid feats: fp32 -> bf16, fragment order, XOR-swizzled ----
    #pragma unroll
    for (int i = 0; i < 2; ++i) {
        const int q = t + i * THREADS;        // octet: centroid n, feature-octet o
        const int n = q >> 3, o = q & 7;
        const float4 g0 = ((const float4*)cen_feats)[q * 2];
        const float4 g1 = ((const float4*)cen_feats)[q * 2 + 1];
        uint4 d;
        d.x = pk2t(g0.x, g0.y); d.y = pk2t(g0.z, g0.w);
        d.z = pk2t(g1.x, g1.y); d.w = pk2t(g1.z, g1.w);
        const int tile = n >> 4;
        const int np   = n & 15;
        const int f    = o >> 2;
        const int lp   = (np | ((o & 3) << 4)) ^ o;   // XOR bank swizzle (r5-verified)
        ((uint4*)Bl)[(tile * 2 + f) * 64 + lp] = d;
    }
    // ---- stage centroid coord A-frags + the two constant frags ----
    if (t < N_CENTROIDS) {
        const int4 c = ((const int4*)cen_coords)[t];   // {b,x,y,z}
        const float gx = (float)c.y, gy = (float)c.z, gz = (float)c.w, gb = (float)c.x;
        const float cn = fmaf(gx, gx, fmaf(gy, gy, gz * gz));   // exact int
        const float hi = __uint_as_float(__float_as_uint(cn) & 0xFFFF0000u);
        const float lo = cn - hi;                               // int < 256, exact
        uint4 e;
        e.x = pk2t(-2.f * gx, -2.f * gy);
        e.y = pk2t(-2.f * gz, -262144.f * gb);      // -2W*b, W = 2^17
        e.z = pk2t(hi, lo);
        e.w = pk2t(131072.f * gb * gb, 1.0f);       // W*b^2 | 1
        Atab[t] = e;
    } else if (t == N_CENTROIDS) {
        uint4 e; e.x = 0x3F803F80u; e.y = 0u; e.z = 0u; e.w = 0u;   // {1,1,0,...}
        Atab[N_CENTROIDS] = e;
    } else if (t == N_CENTROIDS + 1) {
        uint4 z; z.x = 0u; z.y = 0u; z.z = 0u; z.w = 0u;
        Atab[N_CENTROIDS + 1] = z;
    }

    // ---- this lane's cluster-coord B-frag (col = m) ----
    const int4 rc = ((const int4*)clu_coords)[r0w + m];   // {b,x,y,z}
    union { uint4 u; bf16x8 v; } bc;
    {
        const float px = (float)rc.y, py = (float)rc.z, pz = (float)rc.w, pb = (float)rc.x;
        const float pn  = fmaf(px, px, fmaf(py, py, pz * pz));  // exact int
        const float phi = __uint_as_float(__float_as_uint(pn) & 0xFFFF0000u);
        const float plo = pn - phi;                             // int < 256, exact
        uint4 q0, q1, zz;
        q0.x = pk2t(px, py);
        q0.y = pk2t(pz, pb);
        q0.z = 0x3F803F80u;                         // 1 | 1  (k4,k5)
        q0.w = pk2t(1.0f, phi);                     // 1 | pn_hi (k6,k7)
        q1.x = pk2t(plo, 131072.f * pb * pb);       // pn_lo | W*b^2 (k8,k9)
        q1.y = 0u; q1.z = 0u; q1.w = 0u;
        zz.x = 0u; zz.y = 0u; zz.z = 0u; zz.w = 0u;
        bc.u = (quad == 0) ? q0 : ((quad == 1) ? q1 : zz);
    }
    // per-quad A-frag walk: quad 0 strides through Atab rows; quads 1-3 pin
    // to the constant entries (broadcast reads, conflict-free).
    const int aidx0 = (quad == 0) ? m : (quad == 1 ? N_CENTROIDS : N_CENTROIDS + 1);
    const int astep = (quad == 0) ? 16 : 0;

    // ---- convert B frags to bf16 (perm-truncate) ----
    union { uint4 u; bf16x8 v; } b0, b1;
    b0.u.x = pk2t(bL0.x, bL0.y); b0.u.y = pk2t(bL0.z, bL0.w);
    b0.u.z = pk2t(bH0.x, bH0.y); b0.u.w = pk2t(bH0.z, bH0.w);
    b1.u.x = pk2t(bL1.x, bL1.y); b1.u.y = pk2t(bL1.z, bL1.w);
    b1.u.z = pk2t(bH1.x, bH1.y); b1.u.w = pk2t(bH1.z, bH1.w);

    __syncthreads();

    // ---- pass 1: d^2 via MFMA, then exp(-dist); packed 4 x f16 per reg;
    // f32 row sum. Masked: d2 >= 2^17 -> exp == +0 -> rsum unconditional. ----
    unsigned u16[16];
    float rsum = 0.f;
    int aidx = aidx0;
    #pragma unroll
    for (int tt = 0; tt < 16; ++tt) {
        const uint4 a = Atab[aidx];             // ds_read_b128 (bcast for q1-3)
        aidx += astep;
        union { uint4 u; bf16x8 v; } af;
        af.u = a;
        f32x4 d2 = {0.f, 0.f, 0.f, 0.f};
        d2 = __builtin_amdgcn_mfma_f32_16x16x32_bf16(af.v, bc.v, d2, 0, 0, 0);
        float uu[4];
        #pragma unroll
        for (int i = 0; i < 4; ++i) {
            const float dist = fmaxf(__builtin_sqrtf(d2[i]), 0.1f);
            const float e    = __expf(-dist);   // masked -> +0 exactly
            rsum += e;
            uu[i] = (d2[i] < TH_MASK) ? e : -1.0f;
        }
        u16[tt] = pk4h(uu[0], uu[1], uu[2], uu[3]);
    }
    // combine the 4 quads holding the same cluster (lanes m, m+16, m+32, m+48)
    rsum += __shfl_xor(rsum, 16, 64);
    rsum += __shfl_xor(rsum, 32, 64);
    // rcp guard: denormal sum -> rcp = inf -> 0*inf = NaN. Emit zeros instead.
    const float inv = (rsum > 1e-37f) ? __builtin_amdgcn_rcpf(rsum) : 0.f;

    // ---- pass 2: MFMA (A=centroids, B=clusters) + fused epilogue, tt in
    // PAIRS; per-wave LDS re-stage -> 2 x 1-KB stores of 8 rows x 128 B. ----
    const int sl0 = lane ^ quad;              // inverse swizzle, frag 0
    const int sl1 = sl0 ^ 4;                  // frag 1
    uint4* Stw = St + wave * 128;             // this wave's 2-KB slice

    // write slots (slot = m*8 + (c4 ^ (m&7)), c4 = quad + 4t)
    const int ws0 = m * 8 + (quad ^ (m & 7));
    const int ws1 = m * 8 + ((quad + 4) ^ (m & 7));
    // read slots: row = lane>>3 (0..7), c4r = lane&7; slot = row*8 + (c4r ^ (row&7))
    const int rrow = lane >> 3;
    const int rs   = rrow * 8 + ((lane & 7) ^ (rrow & 7));
    // store bases: instr s covers rows s*8 + rrow, cols j*32 + (lane&7)*4
    const size_t olin = (size_t)(r0w + rrow) * N_CENTROIDS + (lane & 7) * 4;
    float* ob  = out + olin;
    float* wb0 = wsm + olin;                  // diag mirror stream 1
    float* wb1 = wsm + olin + (size_t)N_CLUSTERS * N_CENTROIDS;  // stream 2

    #pragma unroll
    for (int j = 0; j < 8; ++j) {
        const int tt0 = 2 * j, tt1 = 2 * j + 1;
        // tile tt0
        const bf16x8 aC0 = *(const bf16x8*)&Bl[((tt0 * 2 + 0) * 64 + sl0) * 4];
        const bf16x8 aC1 = *(const bf16x8*)&Bl[((tt0 * 2 + 1) * 64 + sl1) * 4];
        f32x4 acc0 = {0.f, 0.f, 0.f, 0.f};
        acc0 = __builtin_amdgcn_mfma_f32_16x16x32_bf16(aC0, b0.v, acc0, 0, 0, 0);
        acc0 = __builtin_amdgcn_mfma_f32_16x16x32_bf16(aC1, b1.v, acc0, 0, 0, 0);
        // tile tt1
        const bf16x8 aD0 = *(const bf16x8*)&Bl[((tt1 * 2 + 0) * 64 + sl0) * 4];
        const bf16x8 aD1 = *(const bf16x8*)&Bl[((tt1 * 2 + 1) * 64 + sl1) * 4];
        f32x4 acc1 = {0.f, 0.f, 0.f, 0.f};
        acc1 = __builtin_amdgcn_mfma_f32_16x16x32_bf16(aD0, b0.v, acc1, 0, 0, 0);
        acc1 = __builtin_amdgcn_mfma_f32_16x16x32_bf16(aD1, b1.v, acc1, 0, 0, 0);

        union { float4 f; uint4 u; } o0, o1;
        {
            const unsigned up = u16[tt0];
            const unsigned uq = u16[tt0] >> 16;
            float uu[4];
            uu[0] = h2f_lo(up); uu[1] = h2f_hi(up);
            uu[2] = h2f_lo(uq); uu[3] = h2f_hi(uq);
            #pragma unroll
            for (int i = 0; i < 4; ++i) {
                float w = acc0[i] * (uu[i] * inv);
                w = fminf(fmaxf(w, -10.f), 10.f);
                (&o0.f.x)[i] = (uu[i] < 0.f) ? MASK_VAL : w;
            }
        }
        {
            const unsigned up = u16[tt1];
            const unsigned uq = u16[tt1] >> 16;
            float uu[4];
            uu[0] = h2f_lo(up); uu[1] = h2f_hi(up);
            uu[2] = h2f_lo(uq); uu[3] = h2f_hi(uq);
            #pragma unroll
            for (int i = 0; i < 4; ++i) {
                float w = acc1[i] * (uu[i] * inv);
                w = fminf(fmaxf(w, -10.f), 10.f);
                (&o1.f.x)[i] = (uu[i] < 0.f) ? MASK_VAL : w;
            }
        }
        // stage 16x32-col chunk (cols j*32 .. j*32+31) in this wave's slice
        Stw[ws0] = o0.u;                       // c4 = quad     (cols 4q..4q+3)
        Stw[ws1] = o1.u;                       // c4 = quad + 4 (cols 16+4q..)
        // read back transposed (compiler inserts lgkmcnt for the LDS dep)
        const uint4 r0 = Stw[rs];              // rows 0..7  of the chunk
        const uint4 r1 = Stw[64 + rs];         // rows 8..15 ((8+row)&7 == row&7)
        // 2 store instrs, each 8 rows x 128-B full-line pieces
        *(uint4*)(ob + (size_t)j * 32)                       = r0;
        *(uint4*)(ob + (size_t)j * 32 + 8 * N_CENTROIDS)     = r1;
        // ---- DIAGNOSTIC mirrors: same data, same pattern, workspace ----
        if (mirror) {
            *(uint4*)(wb0 + (size_t)j * 32)                   = r0;
            *(uint4*)(wb0 + (size_t)j * 32 + 8 * N_CENTROIDS) = r1;
            *(uint4*)(wb1 + (size_t)j * 32)                   = r0;
            *(uint4*)(wb1 + (size_t)j * 32 + 8 * N_CENTROIDS) = r1;
        }
    }
}

extern "C" void kernel_launch(void* const* d_in, const int* in_sizes, int n_in,
                              void* d_out, int out_size, void* d_ws, size_t ws_size,
                              hipStream_t stream) {
    const int*   clu_coords = (const int*)  d_in[0];
    const float* clu_feats  = (const float*)d_in[1];
    const int*   cen_coords = (const int*)  d_in[2];
    const float* cen_feats  = (const float*)d_in[3];
    float* out = (float*)d_out;

    const size_t mirror_bytes = 2ull * N_CLUSTERS * N_CENTROIDS * sizeof(float);
    const int mirror = (d_ws != nullptr && ws_size >= mirror_bytes) ? 1 : 0;

    dim3 grid(N_CLUSTERS / ROWS_PER_BLOCK);   // 512 blocks
    dim3 block(THREADS);                      // 1024 threads = 16 waves
    instance_head_kernel<<<grid, block, 0, stream>>>(
        clu_coords, clu_feats, cen_coords, cen_feats, out, (float*)d_ws, mirror);
}

// Round 10
// 173.255 us; speedup vs baseline: 1.9678x; 1.9678x over previous
//
#include <hip/hip_runtime.h>
#include <hip/hip_fp16.h>

constexpr int N_CLUSTERS   = 131072;
constexpr int N_CENTROIDS  = 256;
constexpr int D_FEAT       = 64;

constexpr int THREADS        = 1024;  // 16 waves
constexpr int ROWS_PER_BLOCK = 256;   // 16 clusters per wave

// Finite-in-bf16 sentinel for masked (cross-batch) outputs.
#define MASK_VAL (-1.0e30f)
// Mask detector: true d^2 <= 3*127^2 = 48387; cross-batch adds W*(db)^2 >= 2^17.
#define TH_MASK  (65536.0f)

typedef __attribute__((ext_vector_type(8))) short bf16x8;   // 8 bf16 (4 VGPRs)
typedef __attribute__((ext_vector_type(4))) float f32x4;    // MFMA C/D
typedef __attribute__((ext_vector_type(4))) unsigned u32x4; // nt-store payload
typedef __attribute__((ext_vector_type(2))) __fp16 h2;      // cvt_pkrtz result

// fp32 pair -> packed bf16 via ONE v_perm_b32 (truncation; exact for the
// integer-valued inputs used here).
static __device__ inline unsigned pk2t(float a, float b) {
    return __builtin_amdgcn_perm(__float_as_uint(b), __float_as_uint(a), 0x07060302u);
}
// fp32 x4 -> packed 4 x f16 in one u32 (2x v_cvt_pkrtz_f16_f32 + 1 v_perm)
static __device__ inline unsigned pk4h(float a, float b, float c, float d) {
    h2 p01 = __builtin_amdgcn_cvt_pkrtz(a, b);
    h2 p23 = __builtin_amdgcn_cvt_pkrtz(c, d);
    unsigned lo, hi;
    __builtin_memcpy(&lo, &p01, 4);
    __builtin_memcpy(&hi, &p23, 4);
    return __builtin_amdgcn_perm(hi, lo, 0x05040100u);
}
static __device__ inline float h2f_lo(unsigned u) {
    return __half2float(__ushort_as_half((unsigned short)(u & 0xFFFFu)));
}
static __device__ inline float h2f_hi(unsigned u) {
    return __half2float(__ushort_as_half((unsigned short)(u >> 16)));
}

// ROUND 20 — mirrors reverted; NONTEMPORAL stores on the 128-B-piece path.
// Round-9 mirror diagnostic: kernel purely memory-rate-bound (VALUBusy 13%,
// MfmaUtil 1.2%, Occupancy 69.5%, LDS conflicts ~0) at ~4.2 TB/s mixed.
// nt rationale (DIFFERENT from round-1's failed nt): round-1 stores were
// 64-B partial-line pieces — L2 write-back merged them; nt broke that (-10us).
// Since round-8 every store piece is a FULL 128-B line: nothing to merge, and
// the 134-MB touch-once stream now only pollutes L2/L3 (evicting shared
// cen_feats/Bl lines; round-9's FETCH blowup showed how sensitive fetch is to
// write-stream cache pressure). nt = evict-first keeps the stream out of the
// caches' way. If this is neutral/negative, the kernel is at its pattern-rate
// roofline (~40 us vs ~25 us fill-rate floor; headline upside ~10 us).
//
// LDS: Bl 32768 + Atab 4128 + St 32768 = 69664 B -> 2 blocks/CU x 16
// waves = 32 waves/CU via __launch_bounds__(1024, 8).
__global__ __launch_bounds__(THREADS, 8)
void instance_head_kernel(const int*   __restrict__ clu_coords,   // [N,4] {b,x,y,z}
                          const float* __restrict__ clu_feats,    // [N,64]
                          const int*   __restrict__ cen_coords,   // [M,4]
                          const float* __restrict__ cen_feats,    // [M,64]
                          float*       __restrict__ out)          // [N,M]
{
    __shared__ unsigned Bl[16 * 2 * 64 * 4];   // 32 KB, centroid-feat fragments
    __shared__ uint4    Atab[N_CENTROIDS + 2]; // 4128 B, coord A-frags + consts
    __shared__ uint4    St[16 * 128];          // 32 KB, per-wave store-stage slices

    const int t    = threadIdx.x;
    const int lane = t & 63;
    const int wave = __builtin_amdgcn_readfirstlane(t >> 6);
    const int m    = lane & 15;
    const int quad = lane >> 4;
    const int r0w  = blockIdx.x * ROWS_PER_BLOCK + wave * 16;

    // ---- B operand: this lane's cluster feats (coalesced fp32 loads) ----
    // frag f, lane: B[col = m][k = f*32 + quad*8 + j]
    const float* bptr = clu_feats + (size_t)(r0w + m) * D_FEAT + quad * 8;
    const float4 bL0 = *(const float4*)(bptr);
    const float4 bH0 = *(const float4*)(bptr + 4);
    const float4 bL1 = *(const float4*)(bptr + 32);
    const float4 bH1 = *(const float4*)(bptr + 36);

    // ---- stage centroid feats: fp32 -> bf16, fragment order, XOR-swizzled ----
    #pragma unroll
    for (int i = 0; i < 2; ++i) {
        const int q = t + i * THREADS;        // octet: centroid n, feature-octet o
        const int n = q >> 3, o = q & 7;
        const float4 g0 = ((const float4*)cen_feats)[q * 2];
        const float4 g1 = ((const float4*)cen_feats)[q * 2 + 1];
        uint4 d;
        d.x = pk2t(g0.x, g0.y); d.y = pk2t(g0.z, g0.w);
        d.z = pk2t(g1.x, g1.y); d.w = pk2t(g1.z, g1.w);
        const int tile = n >> 4;
        const int np   = n & 15;
        const int f    = o >> 2;
        const int lp   = (np | ((o & 3) << 4)) ^ o;   // XOR bank swizzle (r5-verified)
        ((uint4*)Bl)[(tile * 2 + f) * 64 + lp] = d;
    }
    // ---- stage centroid coord A-frags + the two constant frags ----
    if (t < N_CENTROIDS) {
        const int4 c = ((const int4*)cen_coords)[t];   // {b,x,y,z}
        const float gx = (float)c.y, gy = (float)c.z, gz = (float)c.w, gb = (float)c.x;
        const float cn = fmaf(gx, gx, fmaf(gy, gy, gz * gz));   // exact int
        const float hi = __uint_as_float(__float_as_uint(cn) & 0xFFFF0000u);
        const float lo = cn - hi;                               // int < 256, exact
        uint4 e;
        e.x = pk2t(-2.f * gx, -2.f * gy);
        e.y = pk2t(-2.f * gz, -262144.f * gb);      // -2W*b, W = 2^17
        e.z = pk2t(hi, lo);
        e.w = pk2t(131072.f * gb * gb, 1.0f);       // W*b^2 | 1
        Atab[t] = e;
    } else if (t == N_CENTROIDS) {
        uint4 e; e.x = 0x3F803F80u; e.y = 0u; e.z = 0u; e.w = 0u;   // {1,1,0,...}
        Atab[N_CENTROIDS] = e;
    } else if (t == N_CENTROIDS + 1) {
        uint4 z; z.x = 0u; z.y = 0u; z.z = 0u; z.w = 0u;
        Atab[N_CENTROIDS + 1] = z;
    }

    // ---- this lane's cluster-coord B-frag (col = m) ----
    const int4 rc = ((const int4*)clu_coords)[r0w + m];   // {b,x,y,z}
    union { uint4 u; bf16x8 v; } bc;
    {
        const float px = (float)rc.y, py = (float)rc.z, pz = (float)rc.w, pb = (float)rc.x;
        const float pn  = fmaf(px, px, fmaf(py, py, pz * pz));  // exact int
        const float phi = __uint_as_float(__float_as_uint(pn) & 0xFFFF0000u);
        const float plo = pn - phi;                             // int < 256, exact
        uint4 q0, q1, zz;
        q0.x = pk2t(px, py);
        q0.y = pk2t(pz, pb);
        q0.z = 0x3F803F80u;                         // 1 | 1  (k4,k5)
        q0.w = pk2t(1.0f, phi);                     // 1 | pn_hi (k6,k7)
        q1.x = pk2t(plo, 131072.f * pb * pb);       // pn_lo | W*b^2 (k8,k9)
        q1.y = 0u; q1.z = 0u; q1.w = 0u;
        zz.x = 0u; zz.y = 0u; zz.z = 0u; zz.w = 0u;
        bc.u = (quad == 0) ? q0 : ((quad == 1) ? q1 : zz);
    }
    // per-quad A-frag walk: quad 0 strides through Atab rows; quads 1-3 pin
    // to the constant entries (broadcast reads, conflict-free).
    const int aidx0 = (quad == 0) ? m : (quad == 1 ? N_CENTROIDS : N_CENTROIDS + 1);
    const int astep = (quad == 0) ? 16 : 0;

    // ---- convert B frags to bf16 (perm-truncate) ----
    union { uint4 u; bf16x8 v; } b0, b1;
    b0.u.x = pk2t(bL0.x, bL0.y); b0.u.y = pk2t(bL0.z, bL0.w);
    b0.u.z = pk2t(bH0.x, bH0.y); b0.u.w = pk2t(bH0.z, bH0.w);
    b1.u.x = pk2t(bL1.x, bL1.y); b1.u.y = pk2t(bL1.z, bL1.w);
    b1.u.z = pk2t(bH1.x, bH1.y); b1.u.w = pk2t(bH1.z, bH1.w);

    __syncthreads();

    // ---- pass 1: d^2 via MFMA, then exp(-dist); packed 4 x f16 per reg;
    // f32 row sum. Masked: d2 >= 2^17 -> exp == +0 -> rsum unconditional. ----
    unsigned u16[16];
    float rsum = 0.f;
    int aidx = aidx0;
    #pragma unroll
    for (int tt = 0; tt < 16; ++tt) {
        const uint4 a = Atab[aidx];             // ds_read_b128 (bcast for q1-3)
        aidx += astep;
        union { uint4 u; bf16x8 v; } af;
        af.u = a;
        f32x4 d2 = {0.f, 0.f, 0.f, 0.f};
        d2 = __builtin_amdgcn_mfma_f32_16x16x32_bf16(af.v, bc.v, d2, 0, 0, 0);
        float uu[4];
        #pragma unroll
        for (int i = 0; i < 4; ++i) {
            const float dist = fmaxf(__builtin_sqrtf(d2[i]), 0.1f);
            const float e    = __expf(-dist);   // masked -> +0 exactly
            rsum += e;
            uu[i] = (d2[i] < TH_MASK) ? e : -1.0f;
        }
        u16[tt] = pk4h(uu[0], uu[1], uu[2], uu[3]);
    }
    // combine the 4 quads holding the same cluster (lanes m, m+16, m+32, m+48)
    rsum += __shfl_xor(rsum, 16, 64);
    rsum += __shfl_xor(rsum, 32, 64);
    // rcp guard: denormal sum -> rcp = inf -> 0*inf = NaN. Emit zeros instead.
    const float inv = (rsum > 1e-37f) ? __builtin_amdgcn_rcpf(rsum) : 0.f;

    // ---- pass 2: MFMA (A=centroids, B=clusters) + fused epilogue, tt in
    // PAIRS; per-wave LDS re-stage -> 2 x 1-KB nt stores of 8 rows x 128 B. ----
    const int sl0 = lane ^ quad;              // inverse swizzle, frag 0
    const int sl1 = sl0 ^ 4;                  // frag 1
    uint4* Stw = St + wave * 128;             // this wave's 2-KB slice

    // write slots (slot = m*8 + (c4 ^ (m&7)), c4 = quad + 4t)
    const int ws0 = m * 8 + (quad ^ (m & 7));
    const int ws1 = m * 8 + ((quad + 4) ^ (m & 7));
    // read slots: row = lane>>3 (0..7), c4r = lane&7; slot = row*8 + (c4r ^ (row&7))
    const int rrow = lane >> 3;
    const int rs   = rrow * 8 + ((lane & 7) ^ (rrow & 7));
    // store bases: instr s covers rows s*8 + rrow, cols j*32 + (lane&7)*4
    float* ob = out + (size_t)(r0w + rrow) * N_CENTROIDS + (lane & 7) * 4;

    #pragma unroll
    for (int j = 0; j < 8; ++j) {
        const int tt0 = 2 * j, tt1 = 2 * j + 1;
        // tile tt0
        const bf16x8 aC0 = *(const bf16x8*)&Bl[((tt0 * 2 + 0) * 64 + sl0) * 4];
        const bf16x8 aC1 = *(const bf16x8*)&Bl[((tt0 * 2 + 1) * 64 + sl1) * 4];
        f32x4 acc0 = {0.f, 0.f, 0.f, 0.f};
        acc0 = __builtin_amdgcn_mfma_f32_16x16x32_bf16(aC0, b0.v, acc0, 0, 0, 0);
        acc0 = __builtin_amdgcn_mfma_f32_16x16x32_bf16(aC1, b1.v, acc0, 0, 0, 0);
        // tile tt1
        const bf16x8 aD0 = *(const bf16x8*)&Bl[((tt1 * 2 + 0) * 64 + sl0) * 4];
        const bf16x8 aD1 = *(const bf16x8*)&Bl[((tt1 * 2 + 1) * 64 + sl1) * 4];
        f32x4 acc1 = {0.f, 0.f, 0.f, 0.f};
        acc1 = __builtin_amdgcn_mfma_f32_16x16x32_bf16(aD0, b0.v, acc1, 0, 0, 0);
        acc1 = __builtin_amdgcn_mfma_f32_16x16x32_bf16(aD1, b1.v, acc1, 0, 0, 0);

        union { float4 f; uint4 u; } o0, o1;
        {
            const unsigned up = u16[tt0];
            const unsigned uq = u16[tt0] >> 16;
            float uu[4];
            uu[0] = h2f_lo(up); uu[1] = h2f_hi(up);
            uu[2] = h2f_lo(uq); uu[3] = h2f_hi(uq);
            #pragma unroll
            for (int i = 0; i < 4; ++i) {
                float w = acc0[i] * (uu[i] * inv);
                w = fminf(fmaxf(w, -10.f), 10.f);
                (&o0.f.x)[i] = (uu[i] < 0.f) ? MASK_VAL : w;
            }
        }
        {
            const unsigned up = u16[tt1];
            const unsigned uq = u16[tt1] >> 16;
            float uu[4];
            uu[0] = h2f_lo(up); uu[1] = h2f_hi(up);
            uu[2] = h2f_lo(uq); uu[3] = h2f_hi(uq);
            #pragma unroll
            for (int i = 0; i < 4; ++i) {
                float w = acc1[i] * (uu[i] * inv);
                w = fminf(fmaxf(w, -10.f), 10.f);
                (&o1.f.x)[i] = (uu[i] < 0.f) ? MASK_VAL : w;
            }
        }
        // stage 16x32-col chunk (cols j*32 .. j*32+31) in this wave's slice
        Stw[ws0] = o0.u;                       // c4 = quad     (cols 4q..4q+3)
        Stw[ws1] = o1.u;                       // c4 = quad + 4 (cols 16+4q..)
        // read back transposed (compiler inserts lgkmcnt for the LDS dep)
        const uint4 r0 = Stw[rs];              // rows 0..7  of the chunk
        const uint4 r1 = Stw[64 + rs];         // rows 8..15 ((8+row)&7 == row&7)
        // 2 nt store instrs, each 8 rows x 128-B FULL-LINE pieces (evict-first:
        // touch-once stream stays out of L2/L3's way; see round-20 header note)
        u32x4 s0, s1;
        s0.x = r0.x; s0.y = r0.y; s0.z = r0.z; s0.w = r0.w;
        s1.x = r1.x; s1.y = r1.y; s1.z = r1.z; s1.w = r1.w;
        __builtin_nontemporal_store(s0, (u32x4*)(ob + (size_t)j * 32));
        __builtin_nontemporal_store(s1, (u32x4*)(ob + (size_t)j * 32 + 8 * N_CENTROIDS));
    }
}

extern "C" void kernel_launch(void* const* d_in, const int* in_sizes, int n_in,
                              void* d_out, int out_size, void* d_ws, size_t ws_size,
                              hipStream_t stream) {
    const int*   clu_coords = (const int*)  d_in[0];
    const float* clu_feats  = (const float*)d_in[1];
    const int*   cen_coords = (const int*)  d_in[2];
    const float* cen_feats  = (const float*)d_in[3];
    float* out = (float*)d_out;

    dim3 grid(N_CLUSTERS / ROWS_PER_BLOCK);   // 512 blocks
    dim3 block(THREADS);                      // 1024 threads = 16 waves
    instance_head_kernel<<<grid, block, 0, stream>>>(
        clu_coords, clu_feats, cen_coords, cen_feats, out);
}

// Round 11
// 165.614 us; speedup vs baseline: 2.0586x; 1.0461x over previous
//
#include <hip/hip_runtime.h>
#include <hip/hip_fp16.h>

constexpr int N_CLUSTERS   = 131072;
constexpr int N_CENTROIDS  = 256;
constexpr int D_FEAT       = 64;

constexpr int THREADS        = 1024;  // 16 waves
constexpr int ROWS_PER_BLOCK = 256;   // 16 clusters per wave

// Finite-in-bf16 sentinel for masked (cross-batch) outputs.
#define MASK_VAL (-1.0e30f)
// Mask detector: true d^2 <= 3*127^2 = 48387; cross-batch adds W*(db)^2 >= 2^17.
#define TH_MASK  (65536.0f)

typedef __attribute__((ext_vector_type(8))) short bf16x8;   // 8 bf16 (4 VGPRs)
typedef __attribute__((ext_vector_type(4))) float f32x4;    // MFMA C/D
typedef __attribute__((ext_vector_type(2))) __fp16 h2;      // cvt_pkrtz result

// fp32 pair -> packed bf16 via ONE v_perm_b32 (truncation; exact for the
// integer-valued inputs used here).
static __device__ inline unsigned pk2t(float a, float b) {
    return __builtin_amdgcn_perm(__float_as_uint(b), __float_as_uint(a), 0x07060302u);
}
// fp32 x4 -> packed 4 x f16 in one u32 (2x v_cvt_pkrtz_f16_f32 + 1 v_perm)
static __device__ inline unsigned pk4h(float a, float b, float c, float d) {
    h2 p01 = __builtin_amdgcn_cvt_pkrtz(a, b);
    h2 p23 = __builtin_amdgcn_cvt_pkrtz(c, d);
    unsigned lo, hi;
    __builtin_memcpy(&lo, &p01, 4);
    __builtin_memcpy(&hi, &p23, 4);
    return __builtin_amdgcn_perm(hi, lo, 0x05040100u);
}
static __device__ inline float h2f_lo(unsigned u) {
    return __half2float(__ushort_as_half((unsigned short)(u & 0xFFFFu)));
}
static __device__ inline float h2f_hi(unsigned u) {
    return __half2float(__ushort_as_half((unsigned short)(u >> 16)));
}

// ROUND 21 — software-pipelined epilogue; nt reverted (measured neutral, r20).
// Decomposition (r8-r10): kernel ~40 us = ~6 us read burst + ~2 us pass-1 +
// ~30 us store burst (134 MB @ ~4.5 TB/s vs fill 6.8). Last zero-cost lever:
// the per-j chain {ds_write -> lgkmcnt -> ds_read -> store} puts a ~240-cy
// LDS round-trip in front of every 2-KB store issue. Pipeline: per iteration,
// compute chunk j and WRITE its slots, but READ+STORE chunk j-1 — the
// write(j)->read(j) distance becomes a full iteration of MFMA+epilogue, so
// the LDS latency is hidden and stores issue early each iteration. Same
// 2-KB wave-private slice (DS ops are wave-ordered: read(j-1) precedes
// write(j) in program order -> no WAR hazard). Epilogue drains chunk 7.
//
// LDS: Bl 32768 + Atab 4128 + St 32768 = 69664 B -> 2 blocks/CU x 16
// waves = 32 waves/CU via __launch_bounds__(1024, 8).
__global__ __launch_bounds__(THREADS, 8)
void instance_head_kernel(const int*   __restrict__ clu_coords,   // [N,4] {b,x,y,z}
                          const float* __restrict__ clu_feats,    // [N,64]
                          const int*   __restrict__ cen_coords,   // [M,4]
                          const float* __restrict__ cen_feats,    // [M,64]
                          float*       __restrict__ out)          // [N,M]
{
    __shared__ unsigned Bl[16 * 2 * 64 * 4];   // 32 KB, centroid-feat fragments
    __shared__ uint4    Atab[N_CENTROIDS + 2]; // 4128 B, coord A-frags + consts
    __shared__ uint4    St[16 * 128];          // 32 KB, per-wave store-stage slices

    const int t    = threadIdx.x;
    const int lane = t & 63;
    const int wave = __builtin_amdgcn_readfirstlane(t >> 6);
    const int m    = lane & 15;
    const int quad = lane >> 4;
    const int r0w  = blockIdx.x * ROWS_PER_BLOCK + wave * 16;

    // ---- B operand: this lane's cluster feats (coalesced fp32 loads) ----
    // frag f, lane: B[col = m][k = f*32 + quad*8 + j]
    const float* bptr = clu_feats + (size_t)(r0w + m) * D_FEAT + quad * 8;
    const float4 bL0 = *(const float4*)(bptr);
    const float4 bH0 = *(const float4*)(bptr + 4);
    const float4 bL1 = *(const float4*)(bptr + 32);
    const float4 bH1 = *(const float4*)(bptr + 36);

    // ---- stage centroid feats: fp32 -> bf16, fragment order, XOR-swizzled ----
    #pragma unroll
    for (int i = 0; i < 2; ++i) {
        const int q = t + i * THREADS;        // octet: centroid n, feature-octet o
        const int n = q >> 3, o = q & 7;
        const float4 g0 = ((const float4*)cen_feats)[q * 2];
        const float4 g1 = ((const float4*)cen_feats)[q * 2 + 1];
        uint4 d;
        d.x = pk2t(g0.x, g0.y); d.y = pk2t(g0.z, g0.w);
        d.z = pk2t(g1.x, g1.y); d.w = pk2t(g1.z, g1.w);
        const int tile = n >> 4;
        const int np   = n & 15;
        const int f    = o >> 2;
        const int lp   = (np | ((o & 3) << 4)) ^ o;   // XOR bank swizzle (r5-verified)
        ((uint4*)Bl)[(tile * 2 + f) * 64 + lp] = d;
    }
    // ---- stage centroid coord A-frags + the two constant frags ----
    if (t < N_CENTROIDS) {
        const int4 c = ((const int4*)cen_coords)[t];   // {b,x,y,z}
        const float gx = (float)c.y, gy = (float)c.z, gz = (float)c.w, gb = (float)c.x;
        const float cn = fmaf(gx, gx, fmaf(gy, gy, gz * gz));   // exact int
        const float hi = __uint_as_float(__float_as_uint(cn) & 0xFFFF0000u);
        const float lo = cn - hi;                               // int < 256, exact
        uint4 e;
        e.x = pk2t(-2.f * gx, -2.f * gy);
        e.y = pk2t(-2.f * gz, -262144.f * gb);      // -2W*b, W = 2^17
        e.z = pk2t(hi, lo);
        e.w = pk2t(131072.f * gb * gb, 1.0f);       // W*b^2 | 1
        Atab[t] = e;
    } else if (t == N_CENTROIDS) {
        uint4 e; e.x = 0x3F803F80u; e.y = 0u; e.z = 0u; e.w = 0u;   // {1,1,0,...}
        Atab[N_CENTROIDS] = e;
    } else if (t == N_CENTROIDS + 1) {
        uint4 z; z.x = 0u; z.y = 0u; z.z = 0u; z.w = 0u;
        Atab[N_CENTROIDS + 1] = z;
    }

    // ---- this lane's cluster-coord B-frag (col = m) ----
    const int4 rc = ((const int4*)clu_coords)[r0w + m];   // {b,x,y,z}
    union { uint4 u; bf16x8 v; } bc;
    {
        const float px = (float)rc.y, py = (float)rc.z, pz = (float)rc.w, pb = (float)rc.x;
        const float pn  = fmaf(px, px, fmaf(py, py, pz * pz));  // exact int
        const float phi = __uint_as_float(__float_as_uint(pn) & 0xFFFF0000u);
        const float plo = pn - phi;                             // int < 256, exact
        uint4 q0, q1, zz;
        q0.x = pk2t(px, py);
        q0.y = pk2t(pz, pb);
        q0.z = 0x3F803F80u;                         // 1 | 1  (k4,k5)
        q0.w = pk2t(1.0f, phi);                     // 1 | pn_hi (k6,k7)
        q1.x = pk2t(plo, 131072.f * pb * pb);       // pn_lo | W*b^2 (k8,k9)
        q1.y = 0u; q1.z = 0u; q1.w = 0u;
        zz.x = 0u; zz.y = 0u; zz.z = 0u; zz.w = 0u;
        bc.u = (quad == 0) ? q0 : ((quad == 1) ? q1 : zz);
    }
    // per-quad A-frag walk: quad 0 strides through Atab rows; quads 1-3 pin
    // to the constant entries (broadcast reads, conflict-free).
    const int aidx0 = (quad == 0) ? m : (quad == 1 ? N_CENTROIDS : N_CENTROIDS + 1);
    const int astep = (quad == 0) ? 16 : 0;

    // ---- convert B frags to bf16 (perm-truncate) ----
    union { uint4 u; bf16x8 v; } b0, b1;
    b0.u.x = pk2t(bL0.x, bL0.y); b0.u.y = pk2t(bL0.z, bL0.w);
    b0.u.z = pk2t(bH0.x, bH0.y); b0.u.w = pk2t(bH0.z, bH0.w);
    b1.u.x = pk2t(bL1.x, bL1.y); b1.u.y = pk2t(bL1.z, bL1.w);
    b1.u.z = pk2t(bH1.x, bH1.y); b1.u.w = pk2t(bH1.z, bH1.w);

    __syncthreads();

    // ---- pass 1: d^2 via MFMA, then exp(-dist); packed 4 x f16 per reg;
    // f32 row sum. Masked: d2 >= 2^17 -> exp == +0 -> rsum unconditional. ----
    unsigned u16[16];
    float rsum = 0.f;
    int aidx = aidx0;
    #pragma unroll
    for (int tt = 0; tt < 16; ++tt) {
        const uint4 a = Atab[aidx];             // ds_read_b128 (bcast for q1-3)
        aidx += astep;
        union { uint4 u; bf16x8 v; } af;
        af.u = a;
        f32x4 d2 = {0.f, 0.f, 0.f, 0.f};
        d2 = __builtin_amdgcn_mfma_f32_16x16x32_bf16(af.v, bc.v, d2, 0, 0, 0);
        float uu[4];
        #pragma unroll
        for (int i = 0; i < 4; ++i) {
            const float dist = fmaxf(__builtin_sqrtf(d2[i]), 0.1f);
            const float e    = __expf(-dist);   // masked -> +0 exactly
            rsum += e;
            uu[i] = (d2[i] < TH_MASK) ? e : -1.0f;
        }
        u16[tt] = pk4h(uu[0], uu[1], uu[2], uu[3]);
    }
    // combine the 4 quads holding the same cluster (lanes m, m+16, m+32, m+48)
    rsum += __shfl_xor(rsum, 16, 64);
    rsum += __shfl_xor(rsum, 32, 64);
    // rcp guard: denormal sum -> rcp = inf -> 0*inf = NaN. Emit zeros instead.
    const float inv = (rsum > 1e-37f) ? __builtin_amdgcn_rcpf(rsum) : 0.f;

    // ---- pass 2: MFMA (A=centroids, B=clusters) + fused epilogue, tt in
    // PAIRS; SOFTWARE-PIPELINED per-wave LDS re-stage: iteration j computes &
    // writes chunk j, reads & stores chunk j-1 (same 2-KB slice; DS ops are
    // wave-ordered so read(j-1) before write(j) is hazard-free). ----
    const int sl0 = lane ^ quad;              // inverse swizzle, frag 0
    const int sl1 = sl0 ^ 4;                  // frag 1
    uint4* Stw = St + wave * 128;             // this wave's 2-KB slice

    // write slots (slot = m*8 + (c4 ^ (m&7)), c4 = quad + 4t)
    const int ws0 = m * 8 + (quad ^ (m & 7));
    const int ws1 = m * 8 + ((quad + 4) ^ (m & 7));
    // read slots: row = lane>>3 (0..7), c4r = lane&7; slot = row*8 + (c4r ^ (row&7))
    const int rrow = lane >> 3;
    const int rs   = rrow * 8 + ((lane & 7) ^ (rrow & 7));
    // store bases: instr s covers rows s*8 + rrow, cols j*32 + (lane&7)*4
    float* ob = out + (size_t)(r0w + rrow) * N_CENTROIDS + (lane & 7) * 4;

    #pragma unroll
    for (int j = 0; j < 8; ++j) {
        // ---- compute chunk j (independent of the St slice) ----
        const int tt0 = 2 * j, tt1 = 2 * j + 1;
        const bf16x8 aC0 = *(const bf16x8*)&Bl[((tt0 * 2 + 0) * 64 + sl0) * 4];
        const bf16x8 aC1 = *(const bf16x8*)&Bl[((tt0 * 2 + 1) * 64 + sl1) * 4];
        f32x4 acc0 = {0.f, 0.f, 0.f, 0.f};
        acc0 = __builtin_amdgcn_mfma_f32_16x16x32_bf16(aC0, b0.v, acc0, 0, 0, 0);
        acc0 = __builtin_amdgcn_mfma_f32_16x16x32_bf16(aC1, b1.v, acc0, 0, 0, 0);
        const bf16x8 aD0 = *(const bf16x8*)&Bl[((tt1 * 2 + 0) * 64 + sl0) * 4];
        const bf16x8 aD1 = *(const bf16x8*)&Bl[((tt1 * 2 + 1) * 64 + sl1) * 4];
        f32x4 acc1 = {0.f, 0.f, 0.f, 0.f};
        acc1 = __builtin_amdgcn_mfma_f32_16x16x32_bf16(aD0, b0.v, acc1, 0, 0, 0);
        acc1 = __builtin_amdgcn_mfma_f32_16x16x32_bf16(aD1, b1.v, acc1, 0, 0, 0);

        union { float4 f; uint4 u; } o0, o1;
        {
            const unsigned up = u16[tt0];
            const unsigned uq = u16[tt0] >> 16;
            float uu[4];
            uu[0] = h2f_lo(up); uu[1] = h2f_hi(up);
            uu[2] = h2f_lo(uq); uu[3] = h2f_hi(uq);
            #pragma unroll
            for (int i = 0; i < 4; ++i) {
                float w = acc0[i] * (uu[i] * inv);
                w = fminf(fmaxf(w, -10.f), 10.f);
                (&o0.f.x)[i] = (uu[i] < 0.f) ? MASK_VAL : w;
            }
        }
        {
            const unsigned up = u16[tt1];
            const unsigned uq = u16[tt1] >> 16;
            float uu[4];
            uu[0] = h2f_lo(up); uu[1] = h2f_hi(up);
            uu[2] = h2f_lo(uq); uu[3] = h2f_hi(uq);
            #pragma unroll
            for (int i = 0; i < 4; ++i) {
                float w = acc1[i] * (uu[i] * inv);
                w = fminf(fmaxf(w, -10.f), 10.f);
                (&o1.f.x)[i] = (uu[i] < 0.f) ? MASK_VAL : w;
            }
        }

        // ---- drain chunk j-1: read its slots and store (early in iter) ----
        if (j > 0) {
            const uint4 r0 = Stw[rs];          // rows 0..7  of chunk j-1
            const uint4 r1 = Stw[64 + rs];     // rows 8..15
            *(uint4*)(ob + (size_t)(j - 1) * 32)                   = r0;
            *(uint4*)(ob + (size_t)(j - 1) * 32 + 8 * N_CENTROIDS) = r1;
        }
        // ---- write chunk j into the slice (read j-1 precedes in DS order) ----
        Stw[ws0] = o0.u;                       // c4 = quad     (cols 4q..4q+3)
        Stw[ws1] = o1.u;                       // c4 = quad + 4 (cols 16+4q..)
    }
    // ---- epilogue: drain chunk 7 ----
    {
        const uint4 r0 = Stw[rs];
        const uint4 r1 = Stw[64 + rs];
        *(uint4*)(ob + (size_t)7 * 32)                   = r0;
        *(uint4*)(ob + (size_t)7 * 32 + 8 * N_CENTROIDS) = r1;
    }
}

extern "C" void kernel_launch(void* const* d_in, const int* in_sizes, int n_in,
                              void* d_out, int out_size, void* d_ws, size_t ws_size,
                              hipStream_t stream) {
    const int*   clu_coords = (const int*)  d_in[0];
    const float* clu_feats  = (const float*)d_in[1];
    const int*   cen_coords = (const int*)  d_in[2];
    const float* cen_feats  = (const float*)d_in[3];
    float* out = (float*)d_out;

    dim3 grid(N_CLUSTERS / ROWS_PER_BLOCK);   // 512 blocks
    dim3 block(THREADS);                      // 1024 threads = 16 waves
    instance_head_kernel<<<grid, block, 0, stream>>>(
        clu_coords, clu_feats, cen_coords, cen_feats, out);
}

// Round 12
// 163.341 us; speedup vs baseline: 2.0873x; 1.0139x over previous
//
#include <hip/hip_runtime.h>
#include <hip/hip_fp16.h>

constexpr int N_CLUSTERS   = 131072;
constexpr int N_CENTROIDS  = 256;
constexpr int D_FEAT       = 64;

constexpr int THREADS        = 1024;  // 16 waves
constexpr int ROWS_PER_BLOCK = 256;   // 16 clusters per wave

// Finite-in-bf16 sentinel for masked (cross-batch) outputs.
#define MASK_VAL (-1.0e30f)
// Mask detector: true d^2 <= 3*127^2 = 48387; cross-batch adds W*(db)^2 >= 2^17.
#define TH_MASK  (65536.0f)

typedef __attribute__((ext_vector_type(8))) short bf16x8;   // 8 bf16 (4 VGPRs)
typedef __attribute__((ext_vector_type(4))) float f32x4;    // MFMA C/D
typedef __attribute__((ext_vector_type(2))) __fp16 h2;      // cvt_pkrtz result

// fp32 pair -> packed bf16 via ONE v_perm_b32 (truncation; exact for the
// integer-valued inputs used here).
static __device__ inline unsigned pk2t(float a, float b) {
    return __builtin_amdgcn_perm(__float_as_uint(b), __float_as_uint(a), 0x07060302u);
}
// fp32 x4 -> packed 4 x f16 in one u32 (2x v_cvt_pkrtz_f16_f32 + 1 v_perm)
static __device__ inline unsigned pk4h(float a, float b, float c, float d) {
    h2 p01 = __builtin_amdgcn_cvt_pkrtz(a, b);
    h2 p23 = __builtin_amdgcn_cvt_pkrtz(c, d);
    unsigned lo, hi;
    __builtin_memcpy(&lo, &p01, 4);
    __builtin_memcpy(&hi, &p23, 4);
    return __builtin_amdgcn_perm(hi, lo, 0x05040100u);
}
static __device__ inline float h2f_lo(unsigned u) {
    return __half2float(__ushort_as_half((unsigned short)(u & 0xFFFFu)));
}
static __device__ inline float h2f_hi(unsigned u) {
    return __half2float(__ushort_as_half((unsigned short)(u >> 16)));
}

// ROUND 22 — FINAL: revert to the round-8/18 configuration (best measured,
// 163.5 us at nominal fills). The r21 software-pipelined epilogue measured
// neutral-to-negative (TLP at 69% occupancy already hides the LDS round-trip).
// Campaign summary (counter-verified):
//   - MFMA-computed distances: VALUBusy 80% -> 13% (r13/r16 diagnostics)
//   - 1024-thread blocks, 1 generation: Occupancy 19% -> 69% (r17)
//   - 128-B full-line stores via per-wave LDS re-stage: +4.5 us (r18)
//   - nt stores: neutral (r20); pipelined epilogue: -2 us (r21) -> reverted
// Remaining state: memory-rate-bound store burst (134 MB @ ~4.5 TB/s pattern
// rate vs 6.8 TB/s fill rate); VALUBusy 13%, MfmaUtil 1.2%, conflicts ~0.
// All mechanism-backed levers on the residual ~10 us have been measured.
//
// LDS: Bl 32768 + Atab 4128 + St 32768 = 69664 B -> 2 blocks/CU x 16
// waves = 32 waves/CU via __launch_bounds__(1024, 8).
__global__ __launch_bounds__(THREADS, 8)
void instance_head_kernel(const int*   __restrict__ clu_coords,   // [N,4] {b,x,y,z}
                          const float* __restrict__ clu_feats,    // [N,64]
                          const int*   __restrict__ cen_coords,   // [M,4]
                          const float* __restrict__ cen_feats,    // [M,64]
                          float*       __restrict__ out)          // [N,M]
{
    __shared__ unsigned Bl[16 * 2 * 64 * 4];   // 32 KB, centroid-feat fragments
    __shared__ uint4    Atab[N_CENTROIDS + 2]; // 4128 B, coord A-frags + consts
    __shared__ uint4    St[16 * 128];          // 32 KB, per-wave store-stage slices

    const int t    = threadIdx.x;
    const int lane = t & 63;
    const int wave = __builtin_amdgcn_readfirstlane(t >> 6);
    const int m    = lane & 15;
    const int quad = lane >> 4;
    const int r0w  = blockIdx.x * ROWS_PER_BLOCK + wave * 16;

    // ---- B operand: this lane's cluster feats (coalesced fp32 loads) ----
    // frag f, lane: B[col = m][k = f*32 + quad*8 + j]
    const float* bptr = clu_feats + (size_t)(r0w + m) * D_FEAT + quad * 8;
    const float4 bL0 = *(const float4*)(bptr);
    const float4 bH0 = *(const float4*)(bptr + 4);
    const float4 bL1 = *(const float4*)(bptr + 32);
    const float4 bH1 = *(const float4*)(bptr + 36);

    // ---- stage centroid feats: fp32 -> bf16, fragment order, XOR-swizzled ----
    #pragma unroll
    for (int i = 0; i < 2; ++i) {
        const int q = t + i * THREADS;        // octet: centroid n, feature-octet o
        const int n = q >> 3, o = q & 7;
        const float4 g0 = ((const float4*)cen_feats)[q * 2];
        const float4 g1 = ((const float4*)cen_feats)[q * 2 + 1];
        uint4 d;
        d.x = pk2t(g0.x, g0.y); d.y = pk2t(g0.z, g0.w);
        d.z = pk2t(g1.x, g1.y); d.w = pk2t(g1.z, g1.w);
        const int tile = n >> 4;
        const int np   = n & 15;
        const int f    = o >> 2;
        const int lp   = (np | ((o & 3) << 4)) ^ o;   // XOR bank swizzle (r5-verified)
        ((uint4*)Bl)[(tile * 2 + f) * 64 + lp] = d;
    }
    // ---- stage centroid coord A-frags + the two constant frags ----
    if (t < N_CENTROIDS) {
        const int4 c = ((const int4*)cen_coords)[t];   // {b,x,y,z}
        const float gx = (float)c.y, gy = (float)c.z, gz = (float)c.w, gb = (float)c.x;
        const float cn = fmaf(gx, gx, fmaf(gy, gy, gz * gz));   // exact int
        const float hi = __uint_as_float(__float_as_uint(cn) & 0xFFFF0000u);
        const float lo = cn - hi;                               // int < 256, exact
        uint4 e;
        e.x = pk2t(-2.f * gx, -2.f * gy);
        e.y = pk2t(-2.f * gz, -262144.f * gb);      // -2W*b, W = 2^17
        e.z = pk2t(hi, lo);
        e.w = pk2t(131072.f * gb * gb, 1.0f);       // W*b^2 | 1
        Atab[t] = e;
    } else if (t == N_CENTROIDS) {
        uint4 e; e.x = 0x3F803F80u; e.y = 0u; e.z = 0u; e.w = 0u;   // {1,1,0,...}
        Atab[N_CENTROIDS] = e;
    } else if (t == N_CENTROIDS + 1) {
        uint4 z; z.x = 0u; z.y = 0u; z.z = 0u; z.w = 0u;
        Atab[N_CENTROIDS + 1] = z;
    }

    // ---- this lane's cluster-coord B-frag (col = m) ----
    const int4 rc = ((const int4*)clu_coords)[r0w + m];   // {b,x,y,z}
    union { uint4 u; bf16x8 v; } bc;
    {
        const float px = (float)rc.y, py = (float)rc.z, pz = (float)rc.w, pb = (float)rc.x;
        const float pn  = fmaf(px, px, fmaf(py, py, pz * pz));  // exact int
        const float phi = __uint_as_float(__float_as_uint(pn) & 0xFFFF0000u);
        const float plo = pn - phi;                             // int < 256, exact
        uint4 q0, q1, zz;
        q0.x = pk2t(px, py);
        q0.y = pk2t(pz, pb);
        q0.z = 0x3F803F80u;                         // 1 | 1  (k4,k5)
        q0.w = pk2t(1.0f, phi);                     // 1 | pn_hi (k6,k7)
        q1.x = pk2t(plo, 131072.f * pb * pb);       // pn_lo | W*b^2 (k8,k9)
        q1.y = 0u; q1.z = 0u; q1.w = 0u;
        zz.x = 0u; zz.y = 0u; zz.z = 0u; zz.w = 0u;
        bc.u = (quad == 0) ? q0 : ((quad == 1) ? q1 : zz);
    }
    // per-quad A-frag walk: quad 0 strides through Atab rows; quads 1-3 pin
    // to the constant entries (broadcast reads, conflict-free).
    const int aidx0 = (quad == 0) ? m : (quad == 1 ? N_CENTROIDS : N_CENTROIDS + 1);
    const int astep = (quad == 0) ? 16 : 0;

    // ---- convert B frags to bf16 (perm-truncate) ----
    union { uint4 u; bf16x8 v; } b0, b1;
    b0.u.x = pk2t(bL0.x, bL0.y); b0.u.y = pk2t(bL0.z, bL0.w);
    b0.u.z = pk2t(bH0.x, bH0.y); b0.u.w = pk2t(bH0.z, bH0.w);
    b1.u.x = pk2t(bL1.x, bL1.y); b1.u.y = pk2t(bL1.z, bL1.w);
    b1.u.z = pk2t(bH1.x, bH1.y); b1.u.w = pk2t(bH1.z, bH1.w);

    __syncthreads();

    // ---- pass 1: d^2 via MFMA, then exp(-dist); packed 4 x f16 per reg;
    // f32 row sum. Masked: d2 >= 2^17 -> exp == +0 -> rsum unconditional. ----
    unsigned u16[16];
    float rsum = 0.f;
    int aidx = aidx0;
    #pragma unroll
    for (int tt = 0; tt < 16; ++tt) {
        const uint4 a = Atab[aidx];             // ds_read_b128 (bcast for q1-3)
        aidx += astep;
        union { uint4 u; bf16x8 v; } af;
        af.u = a;
        f32x4 d2 = {0.f, 0.f, 0.f, 0.f};
        d2 = __builtin_amdgcn_mfma_f32_16x16x32_bf16(af.v, bc.v, d2, 0, 0, 0);
        float uu[4];
        #pragma unroll
        for (int i = 0; i < 4; ++i) {
            const float dist = fmaxf(__builtin_sqrtf(d2[i]), 0.1f);
            const float e    = __expf(-dist);   // masked -> +0 exactly
            rsum += e;
            uu[i] = (d2[i] < TH_MASK) ? e : -1.0f;
        }
        u16[tt] = pk4h(uu[0], uu[1], uu[2], uu[3]);
    }
    // combine the 4 quads holding the same cluster (lanes m, m+16, m+32, m+48)
    rsum += __shfl_xor(rsum, 16, 64);
    rsum += __shfl_xor(rsum, 32, 64);
    // rcp guard: denormal sum -> rcp = inf -> 0*inf = NaN. Emit zeros instead.
    const float inv = (rsum > 1e-37f) ? __builtin_amdgcn_rcpf(rsum) : 0.f;

    // ---- pass 2: MFMA (A=centroids, B=clusters) + fused epilogue, tt in
    // PAIRS; per-wave LDS re-stage -> 2 x 1-KB stores of 8 rows x 128 B. ----
    const int sl0 = lane ^ quad;              // inverse swizzle, frag 0
    const int sl1 = sl0 ^ 4;                  // frag 1
    uint4* Stw = St + wave * 128;             // this wave's 2-KB slice

    // write slots (slot = m*8 + (c4 ^ (m&7)), c4 = quad + 4t)
    const int ws0 = m * 8 + (quad ^ (m & 7));
    const int ws1 = m * 8 + ((quad + 4) ^ (m & 7));
    // read slots: row = lane>>3 (0..7), c4r = lane&7; slot = row*8 + (c4r ^ (row&7))
    const int rrow = lane >> 3;
    const int rs   = rrow * 8 + ((lane & 7) ^ (rrow & 7));
    // store bases: instr s covers rows s*8 + rrow, cols j*32 + (lane&7)*4
    float* ob = out + (size_t)(r0w + rrow) * N_CENTROIDS + (lane & 7) * 4;

    #pragma unroll
    for (int j = 0; j < 8; ++j) {
        const int tt0 = 2 * j, tt1 = 2 * j + 1;
        // tile tt0
        const bf16x8 aC0 = *(const bf16x8*)&Bl[((tt0 * 2 + 0) * 64 + sl0) * 4];
        const bf16x8 aC1 = *(const bf16x8*)&Bl[((tt0 * 2 + 1) * 64 + sl1) * 4];
        f32x4 acc0 = {0.f, 0.f, 0.f, 0.f};
        acc0 = __builtin_amdgcn_mfma_f32_16x16x32_bf16(aC0, b0.v, acc0, 0, 0, 0);
        acc0 = __builtin_amdgcn_mfma_f32_16x16x32_bf16(aC1, b1.v, acc0, 0, 0, 0);
        // tile tt1
        const bf16x8 aD0 = *(const bf16x8*)&Bl[((tt1 * 2 + 0) * 64 + sl0) * 4];
        const bf16x8 aD1 = *(const bf16x8*)&Bl[((tt1 * 2 + 1) * 64 + sl1) * 4];
        f32x4 acc1 = {0.f, 0.f, 0.f, 0.f};
        acc1 = __builtin_amdgcn_mfma_f32_16x16x32_bf16(aD0, b0.v, acc1, 0, 0, 0);
        acc1 = __builtin_amdgcn_mfma_f32_16x16x32_bf16(aD1, b1.v, acc1, 0, 0, 0);

        union { float4 f; uint4 u; } o0, o1;
        {
            const unsigned up = u16[tt0];
            const unsigned uq = u16[tt0] >> 16;
            float uu[4];
            uu[0] = h2f_lo(up); uu[1] = h2f_hi(up);
            uu[2] = h2f_lo(uq); uu[3] = h2f_hi(uq);
            #pragma unroll
            for (int i = 0; i < 4; ++i) {
                float w = acc0[i] * (uu[i] * inv);
                w = fminf(fmaxf(w, -10.f), 10.f);
                (&o0.f.x)[i] = (uu[i] < 0.f) ? MASK_VAL : w;
            }
        }
        {
            const unsigned up = u16[tt1];
            const unsigned uq = u16[tt1] >> 16;
            float uu[4];
            uu[0] = h2f_lo(up); uu[1] = h2f_hi(up);
            uu[2] = h2f_lo(uq); uu[3] = h2f_hi(uq);
            #pragma unroll
            for (int i = 0; i < 4; ++i) {
                float w = acc1[i] * (uu[i] * inv);
                w = fminf(fmaxf(w, -10.f), 10.f);
                (&o1.f.x)[i] = (uu[i] < 0.f) ? MASK_VAL : w;
            }
        }
        // stage 16x32-col chunk (cols j*32 .. j*32+31) in this wave's slice
        Stw[ws0] = o0.u;                       // c4 = quad     (cols 4q..4q+3)
        Stw[ws1] = o1.u;                       // c4 = quad + 4 (cols 16+4q..)
        // read back transposed (compiler inserts lgkmcnt for the LDS dep)
        const uint4 r0 = Stw[rs];              // rows 0..7  of the chunk
        const uint4 r1 = Stw[64 + rs];         // rows 8..15 ((8+row)&7 == row&7)
        // 2 store instrs, each 8 rows x 128-B full-line pieces
        *(uint4*)(ob + (size_t)j * 32)                       = r0;
        *(uint4*)(ob + (size_t)j * 32 + 8 * N_CENTROIDS)     = r1;
    }
}

extern "C" void kernel_launch(void* const* d_in, const int* in_sizes, int n_in,
                              void* d_out, int out_size, void* d_ws, size_t ws_size,
                              hipStream_t stream) {
    const int*   clu_coords = (const int*)  d_in[0];
    const float* clu_feats  = (const float*)d_in[1];
    const int*   cen_coords = (const int*)  d_in[2];
    const float* cen_feats  = (const float*)d_in[3];
    float* out = (float*)d_out;

    dim3 grid(N_CLUSTERS / ROWS_PER_BLOCK);   // 512 blocks
    dim3 block(THREADS);                      // 1024 threads = 16 waves
    instance_head_kernel<<<grid, block, 0, stream>>>(
        clu_coords, clu_feats, cen_coords, cen_feats, out);
}